// Round 1
// baseline (401.557 us; speedup 1.0000x reference)
//
#include <hip/hip_runtime.h>
#include <cstdint>
#include <cstddef>

typedef _Float16 f16;
typedef _Float16 f16x8 __attribute__((ext_vector_type(8)));
typedef _Float16 f16x4 __attribute__((ext_vector_type(4)));
typedef float    f32x4 __attribute__((ext_vector_type(4)));

#define S_CTX 2048
#define NH 16
#define DH 128

__device__ __forceinline__ void gload16(const void* g, void* l) {
  __builtin_amdgcn_global_load_lds(
      (const __attribute__((address_space(1))) void*)g,
      (__attribute__((address_space(3))) void*)l, 16, 0, 0);
}

// ---------- elementwise: fp32 -> fp16 ----------
__global__ void cvt_f32_f16(const float* __restrict__ in, f16* __restrict__ out) {
  int i = (blockIdx.x * 256 + threadIdx.x) * 4;
  float4 v = *(const float4*)(in + i);
  f16x4 o; o[0] = (f16)v.x; o[1] = (f16)v.y; o[2] = (f16)v.z; o[3] = (f16)v.w;
  *(f16x4*)(out + i) = o;
}

// ---------- weight transpose + convert: W[k][n] fp32 -> Wt[n][k] fp16 ----------
__global__ void wtrans(const float* __restrict__ w0, const float* __restrict__ w1,
                       const float* __restrict__ w2, const float* __restrict__ w3,
                       f16* __restrict__ o0, f16* __restrict__ o1,
                       f16* __restrict__ o2, f16* __restrict__ o3) {
  const float* in; f16* out;
  switch (blockIdx.z) {
    case 0: in = w0; out = o0; break;
    case 1: in = w1; out = o1; break;
    case 2: in = w2; out = o2; break;
    default: in = w3; out = o3; break;
  }
  __shared__ float tl[32][33];
  int x = blockIdx.x * 32 + threadIdx.x;   // n
  int y = blockIdx.y * 32 + threadIdx.y;   // k
#pragma unroll
  for (int r = 0; r < 32; r += 8)
    tl[threadIdx.y + r][threadIdx.x] = in[(size_t)(y + r) * 2048 + x];
  __syncthreads();
  int xo = blockIdx.y * 32 + threadIdx.x;  // k
  int yo = blockIdx.x * 32 + threadIdx.y;  // n
#pragma unroll
  for (int r = 0; r < 32; r += 8)
    out[(size_t)(yo + r) * 2048 + xo] = (f16)tl[threadIdx.x][threadIdx.y + r];
}

// ---------- RoPE tables ----------
__global__ void rope_tab(float* __restrict__ sint, float* __restrict__ cost) {
  int idx = blockIdx.x * 256 + threadIdx.x;   // 2048*64
  int j = idx & 63, s = idx >> 6;
  float invf = __expf(-(float)(2 * j) * (1.0f / 128.0f) * 9.210340371976184f); // base^-2j/128
  float a = (float)s * invf;
  sint[idx] = sinf(a);
  cost[idx] = cosf(a);
}

// ---------- RoPE apply (in-place, [bh][s][128], pairs (j, j+64)) ----------
__global__ void rope_apply(f16* __restrict__ x, const float* __restrict__ sint,
                           const float* __restrict__ cost) {
  int idx = blockIdx.x * 256 + threadIdx.x;   // 2*16*2048*64
  int j = idx & 63;
  int s = (idx >> 6) & 2047;
  int bh = idx >> 17;
  size_t base = ((size_t)bh * S_CTX + s) * DH;
  float x1 = (float)x[base + j], x2 = (float)x[base + j + 64];
  float cv = cost[s * 64 + j], sv = sint[s * 64 + j];
  x[base + j]      = (f16)(x1 * cv - x2 * sv);
  x[base + j + 64] = (f16)(x2 * cv + x1 * sv);
}

// ---------- GEMM: C[4096x2048] = A[4096x2048] * Bt[2048x2048]^T (fp16 in, fp32 acc)
// MODE 0: out f16 [b,h,s,d]   MODE 1: out f16 V^T [b,h,d,s]   MODE 2: out fp32 row-major
template<int MODE>
__global__ __launch_bounds__(256)
void gemm_k(const f16* __restrict__ A, const f16* __restrict__ Bt,
            f16* __restrict__ oh, float* __restrict__ of) {
  __shared__ __align__(16) char smem[16640];
  f16* As = (f16*)smem;            // [128][32], 16B-slot swizzle: slot ^= (row>>1)&3
  f16* Bs = (f16*)(smem + 8192);
  const int tid = threadIdx.x;
  const int lane = tid & 63;
  const int wv = tid >> 6;
  const int wm = wv >> 1, wn = wv & 1;
  const int row0 = blockIdx.y * 128;
  const int col0 = blockIdx.x * 128;

  f32x4 acc[4][4] = {};

  const int c0 = tid, c1 = tid + 256;
  const int ra0 = c0 >> 2, sa0 = (c0 & 3) ^ ((ra0 >> 1) & 3);
  const int ra1 = c1 >> 2, sa1 = (c1 & 3) ^ ((ra1 >> 1) & 3);
  const f16* Ag0 = A + (size_t)(row0 + ra0) * 2048 + sa0 * 8;
  const f16* Ag1 = A + (size_t)(row0 + ra1) * 2048 + sa1 * 8;
  const f16* Bg0 = Bt + (size_t)(col0 + ra0) * 2048 + sa0 * 8;
  const f16* Bg1 = Bt + (size_t)(col0 + ra1) * 2048 + sa1 * 8;
  f16* Al0 = As + c0 * 8; f16* Al1 = As + c1 * 8;
  f16* Bl0 = Bs + c0 * 8; f16* Bl1 = Bs + c1 * 8;

  const int rA0 = wm * 64 + (lane & 15);
  const int rB0 = wn * 64 + (lane & 15);
  const int ls = lane >> 4;

  for (int k0 = 0; k0 < 2048; k0 += 32) {
    __syncthreads();
    gload16(Ag0 + k0, Al0);
    gload16(Ag1 + k0, Al1);
    gload16(Bg0 + k0, Bl0);
    gload16(Bg1 + k0, Bl1);
    __syncthreads();
    f16x8 af[4], bf[4];
#pragma unroll
    for (int i = 0; i < 4; i++) {
      int rA = rA0 + i * 16;
      int rB = rB0 + i * 16;
      af[i] = *(const f16x8*)&As[rA * 32 + ((ls ^ ((rA >> 1) & 3)) << 3)];
      bf[i] = *(const f16x8*)&Bs[rB * 32 + ((ls ^ ((rB >> 1) & 3)) << 3)];
    }
#pragma unroll
    for (int i = 0; i < 4; i++)
#pragma unroll
      for (int j = 0; j < 4; j++)
        acc[i][j] = __builtin_amdgcn_mfma_f32_16x16x32_f16(af[i], bf[j], acc[i][j], 0, 0, 0);
  }

  if (MODE == 0) {
#pragma unroll
    for (int i = 0; i < 4; i++)
#pragma unroll
      for (int j = 0; j < 4; j++)
#pragma unroll
        for (int r = 0; r < 4; r++) {
          int row = row0 + wm * 64 + i * 16 + (lane >> 4) * 4 + r;
          int col = col0 + wn * 64 + j * 16 + (lane & 15);
          int b = row >> 11, s = row & 2047, h = col >> 7, d = col & 127;
          oh[(((size_t)(b * NH + h) * S_CTX + s) << 7) + d] = (f16)acc[i][j][r];
        }
  } else if (MODE == 2) {
#pragma unroll
    for (int i = 0; i < 4; i++)
#pragma unroll
      for (int j = 0; j < 4; j++)
#pragma unroll
        for (int r = 0; r < 4; r++) {
          int row = row0 + wm * 64 + i * 16 + (lane >> 4) * 4 + r;
          int col = col0 + wn * 64 + j * 16 + (lane & 15);
          of[(size_t)row * 2048 + col] = acc[i][j][r];
        }
  } else {
    // MODE 1: V^T epilogue. Block covers rows [row0,row0+128) (one b), cols = head h= blockIdx.x.
    const int b = row0 >> 11, s0 = row0 & 2047, h = blockIdx.x;
    f16* T = (f16*)smem;   // [64][130] padded
    for (int hh = 0; hh < 2; hh++) {
      __syncthreads();
      if (wm == hh) {
#pragma unroll
        for (int i = 0; i < 4; i++)
#pragma unroll
          for (int j = 0; j < 4; j++)
#pragma unroll
            for (int r = 0; r < 4; r++) {
              int rl = i * 16 + (lane >> 4) * 4 + r;          // s-local 0..63
              int cl = wn * 64 + j * 16 + (lane & 15);        // d 0..127
              T[rl * 130 + cl] = (f16)acc[i][j][r];
            }
      }
      __syncthreads();
#pragma unroll
      for (int cc = 0; cc < 4; cc++) {
        int c = tid + cc * 256;
        int d = c >> 3, sc8 = (c & 7) * 8;
        f16x8 v;
#pragma unroll
        for (int e = 0; e < 8; e++) v[e] = T[(sc8 + e) * 130 + d];
        *(f16x8*)&oh[((size_t)(b * NH + h) * DH + d) * S_CTX + s0 + hh * 64 + sc8] = v;
      }
    }
  }
}

// ---------- flash attention, causal, no score scaling ----------
// grid: (32 qtiles, 32 bh). Block: 4 waves, each owns 16 q rows. KVBLK=64.
__global__ __launch_bounds__(256)
void attn_k(const f16* __restrict__ q, const f16* __restrict__ kk,
            const f16* __restrict__ vt, f16* __restrict__ ctx) {
  __shared__ __align__(16) f16 Ks[64 * 128];   // [kv][d], slot ^= kv&7
  __shared__ __align__(16) f16 Vs[128 * 64];   // [d][kv], slot ^= d&7
  __shared__ __align__(16) f16 Pl[4][16 * 64]; // per wave [qr][kv], slot ^= qr&7
  const int tid = threadIdx.x, lane = tid & 63, wv = tid >> 6;
  const int qt = 31 - (int)blockIdx.x;         // heavy blocks first
  const int bh = blockIdx.y;
  const int b = bh >> 4, h = bh & 15;
  const size_t plane = (size_t)bh * (S_CTX * DH);
  const f16* Qp = q + plane;
  const f16* Kp = kk + plane;
  const f16* Vp = vt + plane;
  const int q0 = qt * 64;

  f16x8 qf[4];
  {
    const f16* qq = Qp + (size_t)(q0 + wv * 16 + (lane & 15)) * DH + ((lane >> 4) * 8);
#pragma unroll
    for (int ks = 0; ks < 4; ks++) qf[ks] = *(const f16x8*)(qq + ks * 32);
  }
  float m_[4], l_[4];
  f32x4 o[8] = {};
#pragma unroll
  for (int r = 0; r < 4; r++) { m_[r] = -3e38f; l_[r] = 0.f; }

  for (int t = 0; t <= qt; t++) {
    __syncthreads();
#pragma unroll
    for (int j = 0; j < 4; j++) {
      int c = tid + j * 256;
      int row = c >> 4, sl = (c & 15) ^ (row & 7);
      gload16(Kp + (size_t)(t * 64 + row) * DH + sl * 8, Ks + c * 8);
    }
#pragma unroll
    for (int j = 0; j < 4; j++) {
      int c = tid + j * 256;
      int row = c >> 3, sl = (c & 7) ^ (row & 7);
      gload16(Vp + (size_t)row * S_CTX + t * 64 + sl * 8, Vs + c * 8);
    }
    __syncthreads();

    // S = Q K^T
    f32x4 st[4] = {};
#pragma unroll
    for (int n = 0; n < 4; n++) {
      int rK = n * 16 + (lane & 15);
#pragma unroll
      for (int ks = 0; ks < 4; ks++) {
        int slot = ks * 4 + (lane >> 4);
        f16x8 kf = *(const f16x8*)&Ks[rK * 128 + ((slot ^ (rK & 7)) << 3)];
        st[n] = __builtin_amdgcn_mfma_f32_16x16x32_f16(qf[ks], kf, st[n], 0, 0, 0);
      }
    }
    if (t == qt) {
#pragma unroll
      for (int n = 0; n < 4; n++)
#pragma unroll
        for (int r = 0; r < 4; r++) {
          int kvc = n * 16 + (lane & 15);
          int qr = wv * 16 + (lane >> 4) * 4 + r;
          if (kvc > qr) st[n][r] = -3e38f;
        }
    }
    // online softmax (per q-row; rows live in 16-lane groups, 4 regs each)
    float mx[4];
#pragma unroll
    for (int r = 0; r < 4; r++)
      mx[r] = fmaxf(fmaxf(st[0][r], st[1][r]), fmaxf(st[2][r], st[3][r]));
#pragma unroll
    for (int msk = 1; msk < 16; msk <<= 1)
#pragma unroll
      for (int r = 0; r < 4; r++) mx[r] = fmaxf(mx[r], __shfl_xor(mx[r], msk));
    float al[4];
#pragma unroll
    for (int r = 0; r < 4; r++) {
      float nm = fmaxf(m_[r], mx[r]);
      al[r] = __expf(m_[r] - nm);
      m_[r] = nm;
    }
    float ps[4] = {0.f, 0.f, 0.f, 0.f};
    float pvv[4][4];
#pragma unroll
    for (int n = 0; n < 4; n++)
#pragma unroll
      for (int r = 0; r < 4; r++) {
        float p = __expf(st[n][r] - m_[r]);
        pvv[n][r] = p; ps[r] += p;
      }
#pragma unroll
    for (int msk = 1; msk < 16; msk <<= 1)
#pragma unroll
      for (int r = 0; r < 4; r++) ps[r] += __shfl_xor(ps[r], msk);
#pragma unroll
    for (int r = 0; r < 4; r++) l_[r] = l_[r] * al[r] + ps[r];
#pragma unroll
    for (int j = 0; j < 8; j++)
#pragma unroll
      for (int r = 0; r < 4; r++) o[j][r] *= al[r];

    // P -> LDS (C-layout -> A-frag layout)
    f16* Pw = Pl[wv];
#pragma unroll
    for (int n = 0; n < 4; n++)
#pragma unroll
      for (int r = 0; r < 4; r++) {
        int rowp = (lane >> 4) * 4 + r;
        int colp = n * 16 + (lane & 15);
        Pw[rowp * 64 + (((colp >> 3) ^ (rowp & 7)) << 3) + (colp & 7)] = (f16)pvv[n][r];
      }
    // O += P V
#pragma unroll
    for (int ks = 0; ks < 2; ks++) {
      int rowp = lane & 15;
      int slotp = ks * 4 + (lane >> 4);
      f16x8 pa = *(const f16x8*)&Pw[rowp * 64 + ((slotp ^ (rowp & 7)) << 3)];
#pragma unroll
      for (int j = 0; j < 8; j++) {
        int rv = j * 16 + (lane & 15);
        int slotv = ks * 4 + (lane >> 4);
        f16x8 vf = *(const f16x8*)&Vs[rv * 64 + ((slotv ^ (rv & 7)) << 3)];
        o[j] = __builtin_amdgcn_mfma_f32_16x16x32_f16(pa, vf, o[j], 0, 0, 0);
      }
    }
  }

#pragma unroll
  for (int j = 0; j < 8; j++)
#pragma unroll
    for (int r = 0; r < 4; r++) {
      int qr = q0 + wv * 16 + (lane >> 4) * 4 + r;
      int dd = h * 128 + j * 16 + (lane & 15);
      ctx[((size_t)(b * S_CTX + qr) * 2048) + dd] = (f16)(o[j][r] / l_[r]);
    }
}

extern "C" void kernel_launch(void* const* d_in, const int* in_sizes, int n_in,
                              void* d_out, int out_size, void* d_ws, size_t ws_size,
                              hipStream_t stream) {
  (void)in_sizes; (void)n_in; (void)out_size; (void)ws_size;
  const float* x  = (const float*)d_in[0];
  const float* Wq = (const float*)d_in[1];
  const float* Wk = (const float*)d_in[2];
  const float* Wv = (const float*)d_in[3];
  const float* Wo = (const float*)d_in[4];
  float* out = (float*)d_out;
  char* ws = (char*)d_ws;

  // layout (bytes); ctx aliases xb (xb dead after V-projection)
  f16*   xb   = (f16*)(ws);                    // 16,777,216   x fp16 [4096][2048]
  f16*   ctxb = (f16*)(ws);                    // reuse
  f16*   wqT  = (f16*)(ws + 16777216);         // 8,388,608 each, [n][k] fp16
  f16*   wkT  = (f16*)(ws + 25165824);
  f16*   wvT  = (f16*)(ws + 33554432);
  f16*   woT  = (f16*)(ws + 41943040);
  f16*   qb   = (f16*)(ws + 50331648);         // [b,h,s,d] fp16
  f16*   kb   = (f16*)(ws + 67108864);
  f16*   vtb  = (f16*)(ws + 83886080);         // [b,h,d,s] fp16
  float* sint = (float*)(ws + 100663296);      // [2048][64]
  float* cost = (float*)(ws + 101187584);

  rope_tab<<<dim3(512), dim3(256), 0, stream>>>(sint, cost);
  cvt_f32_f16<<<dim3(8192), dim3(256), 0, stream>>>(x, xb);
  wtrans<<<dim3(64, 64, 4), dim3(32, 8), 0, stream>>>(Wq, Wk, Wv, Wo, wqT, wkT, wvT, woT);
  gemm_k<0><<<dim3(16, 32), dim3(256), 0, stream>>>(xb, wqT, qb, nullptr);
  gemm_k<0><<<dim3(16, 32), dim3(256), 0, stream>>>(xb, wkT, kb, nullptr);
  gemm_k<1><<<dim3(16, 32), dim3(256), 0, stream>>>(xb, wvT, vtb, nullptr);
  rope_apply<<<dim3(16384), dim3(256), 0, stream>>>(qb, sint, cost);
  rope_apply<<<dim3(16384), dim3(256), 0, stream>>>(kb, sint, cost);
  attn_k<<<dim3(32, 32), dim3(256), 0, stream>>>(qb, kb, vtb, ctxb);
  gemm_k<2><<<dim3(16, 32), dim3(256), 0, stream>>>(ctxb, woT, nullptr, out);
}

// Round 2
// 332.462 us; speedup vs baseline: 1.2078x; 1.2078x over previous
//
#include <hip/hip_runtime.h>
#include <cstdint>
#include <cstddef>

typedef _Float16 f16;
typedef _Float16 f16x8 __attribute__((ext_vector_type(8)));
typedef _Float16 f16x4 __attribute__((ext_vector_type(4)));
typedef float    f32x4 __attribute__((ext_vector_type(4)));

#define S_CTX 2048
#define NH 16
#define DH 128

__device__ __forceinline__ void gload16(const void* g, void* l) {
  __builtin_amdgcn_global_load_lds(
      (const __attribute__((address_space(1))) void*)g,
      (__attribute__((address_space(3))) void*)l, 16, 0, 0);
}

// ---------- elementwise: fp32 -> fp16 ----------
__global__ void cvt_f32_f16(const float* __restrict__ in, f16* __restrict__ out) {
  int i = (blockIdx.x * 256 + threadIdx.x) * 4;
  float4 v = *(const float4*)(in + i);
  f16x4 o; o[0] = (f16)v.x; o[1] = (f16)v.y; o[2] = (f16)v.z; o[3] = (f16)v.w;
  *(f16x4*)(out + i) = o;
}

// ---------- weight transpose + convert: W[k][n] fp32 -> Wt[n][k] fp16 ----------
__global__ void wtrans(const float* __restrict__ w0, const float* __restrict__ w1,
                       const float* __restrict__ w2, const float* __restrict__ w3,
                       f16* __restrict__ o0, f16* __restrict__ o1,
                       f16* __restrict__ o2, f16* __restrict__ o3) {
  const float* in; f16* out;
  switch (blockIdx.z) {
    case 0: in = w0; out = o0; break;
    case 1: in = w1; out = o1; break;
    case 2: in = w2; out = o2; break;
    default: in = w3; out = o3; break;
  }
  __shared__ float tl[32][33];
  int x = blockIdx.x * 32 + threadIdx.x;   // n
  int y = blockIdx.y * 32 + threadIdx.y;   // k
#pragma unroll
  for (int r = 0; r < 32; r += 8)
    tl[threadIdx.y + r][threadIdx.x] = in[(size_t)(y + r) * 2048 + x];
  __syncthreads();
  int xo = blockIdx.y * 32 + threadIdx.x;  // k
  int yo = blockIdx.x * 32 + threadIdx.y;  // n
#pragma unroll
  for (int r = 0; r < 32; r += 8)
    out[(size_t)(yo + r) * 2048 + xo] = (f16)tl[threadIdx.x][threadIdx.y + r];
}

// ---------- RoPE tables ----------
__global__ void rope_tab(float* __restrict__ sint, float* __restrict__ cost) {
  int idx = blockIdx.x * 256 + threadIdx.x;   // 2048*64
  int j = idx & 63, s = idx >> 6;
  float invf = __expf(-(float)(2 * j) * (1.0f / 128.0f) * 9.210340371976184f); // base^-2j/128
  float a = (float)s * invf;
  sint[idx] = sinf(a);
  cost[idx] = cosf(a);
}

// ---------- RoPE apply (in-place, [bh][s][128], pairs (j, j+64)) ----------
__global__ void rope_apply(f16* __restrict__ x, const float* __restrict__ sint,
                           const float* __restrict__ cost) {
  int idx = blockIdx.x * 256 + threadIdx.x;   // 2*16*2048*64
  int j = idx & 63;
  int s = (idx >> 6) & 2047;
  int bh = idx >> 17;
  size_t base = ((size_t)bh * S_CTX + s) * DH;
  float x1 = (float)x[base + j], x2 = (float)x[base + j + 64];
  float cv = cost[s * 64 + j], sv = sint[s * 64 + j];
  x[base + j]      = (f16)(x1 * cv - x2 * sv);
  x[base + j + 64] = (f16)(x2 * cv + x1 * sv);
}

// ---------- GEMM: C[4096x2048] = A[4096x2048] * Bt[2048x2048]^T (fp16 in, fp32 acc)
// MODE 0: out f16 [b,h,s,d]   MODE 1: out f16 V^T [b,h,d,s]   MODE 2: out fp32 row-major
template<int MODE>
__global__ __launch_bounds__(256)
void gemm_k(const f16* __restrict__ A, const f16* __restrict__ Bt,
            f16* __restrict__ oh, float* __restrict__ of) {
  __shared__ __align__(16) char smem[16640];
  f16* As = (f16*)smem;            // [128][32], 16B-slot swizzle: slot ^= (row>>1)&3
  f16* Bs = (f16*)(smem + 8192);
  const int tid = threadIdx.x;
  const int lane = tid & 63;
  const int wv = tid >> 6;
  const int wm = wv >> 1, wn = wv & 1;
  const int row0 = blockIdx.y * 128;
  const int col0 = blockIdx.x * 128;

  f32x4 acc[4][4] = {};

  const int c0 = tid, c1 = tid + 256;
  const int ra0 = c0 >> 2, sa0 = (c0 & 3) ^ ((ra0 >> 1) & 3);
  const int ra1 = c1 >> 2, sa1 = (c1 & 3) ^ ((ra1 >> 1) & 3);
  const f16* Ag0 = A + (size_t)(row0 + ra0) * 2048 + sa0 * 8;
  const f16* Ag1 = A + (size_t)(row0 + ra1) * 2048 + sa1 * 8;
  const f16* Bg0 = Bt + (size_t)(col0 + ra0) * 2048 + sa0 * 8;
  const f16* Bg1 = Bt + (size_t)(col0 + ra1) * 2048 + sa1 * 8;
  f16* Al0 = As + c0 * 8; f16* Al1 = As + c1 * 8;
  f16* Bl0 = Bs + c0 * 8; f16* Bl1 = Bs + c1 * 8;

  const int rA0 = wm * 64 + (lane & 15);
  const int rB0 = wn * 64 + (lane & 15);
  const int ls = lane >> 4;

  for (int k0 = 0; k0 < 2048; k0 += 32) {
    __syncthreads();
    gload16(Ag0 + k0, Al0);
    gload16(Ag1 + k0, Al1);
    gload16(Bg0 + k0, Bl0);
    gload16(Bg1 + k0, Bl1);
    __syncthreads();
    f16x8 af[4], bf[4];
#pragma unroll
    for (int i = 0; i < 4; i++) {
      int rA = rA0 + i * 16;
      int rB = rB0 + i * 16;
      af[i] = *(const f16x8*)&As[rA * 32 + ((ls ^ ((rA >> 1) & 3)) << 3)];
      bf[i] = *(const f16x8*)&Bs[rB * 32 + ((ls ^ ((rB >> 1) & 3)) << 3)];
    }
#pragma unroll
    for (int i = 0; i < 4; i++)
#pragma unroll
      for (int j = 0; j < 4; j++)
        acc[i][j] = __builtin_amdgcn_mfma_f32_16x16x32_f16(af[i], bf[j], acc[i][j], 0, 0, 0);
  }

  if (MODE == 0) {
#pragma unroll
    for (int i = 0; i < 4; i++)
#pragma unroll
      for (int j = 0; j < 4; j++)
#pragma unroll
        for (int r = 0; r < 4; r++) {
          int row = row0 + wm * 64 + i * 16 + (lane >> 4) * 4 + r;
          int col = col0 + wn * 64 + j * 16 + (lane & 15);
          int b = row >> 11, s = row & 2047, h = col >> 7, d = col & 127;
          oh[(((size_t)(b * NH + h) * S_CTX + s) << 7) + d] = (f16)acc[i][j][r];
        }
  } else if (MODE == 2) {
#pragma unroll
    for (int i = 0; i < 4; i++)
#pragma unroll
      for (int j = 0; j < 4; j++)
#pragma unroll
        for (int r = 0; r < 4; r++) {
          int row = row0 + wm * 64 + i * 16 + (lane >> 4) * 4 + r;
          int col = col0 + wn * 64 + j * 16 + (lane & 15);
          of[(size_t)row * 2048 + col] = acc[i][j][r];
        }
  } else {
    // MODE 1: V^T epilogue. Block covers rows [row0,row0+128) (one b), cols = head h= blockIdx.x.
    const int b = row0 >> 11, s0 = row0 & 2047, h = blockIdx.x;
    f16* T = (f16*)smem;   // [64][130] padded
    for (int hh = 0; hh < 2; hh++) {
      __syncthreads();
      if (wm == hh) {
#pragma unroll
        for (int i = 0; i < 4; i++)
#pragma unroll
          for (int j = 0; j < 4; j++)
#pragma unroll
            for (int r = 0; r < 4; r++) {
              int rl = i * 16 + (lane >> 4) * 4 + r;          // s-local 0..63
              int cl = wn * 64 + j * 16 + (lane & 15);        // d 0..127
              T[rl * 130 + cl] = (f16)acc[i][j][r];
            }
      }
      __syncthreads();
#pragma unroll
      for (int cc = 0; cc < 4; cc++) {
        int c = tid + cc * 256;
        int d = c >> 3, sc8 = (c & 7) * 8;
        f16x8 v;
#pragma unroll
        for (int e = 0; e < 8; e++) v[e] = T[(sc8 + e) * 130 + d];
        *(f16x8*)&oh[((size_t)(b * NH + h) * DH + d) * S_CTX + s0 + hh * 64 + sc8] = v;
      }
    }
  }
}

// ---------- flash attention, causal, no score scaling ----------
// grid: (16 tile-pairs, 32 bh). Block: 4 waves, each owns 16 q rows. KVBLK=64.
// Block i handles qt=i then qt=31-i -> every block does exactly 33 KV iterations
// (causal load balancing; previously block qt did qt+1 iters -> half the CUs idle).
__global__ __launch_bounds__(256)
void attn_k(const f16* __restrict__ q, const f16* __restrict__ kk,
            const f16* __restrict__ vt, f16* __restrict__ ctx) {
  __shared__ __align__(16) f16 Ks[64 * 128];   // [kv][d], slot ^= kv&7
  __shared__ __align__(16) f16 Vs[128 * 64];   // [d][kv], slot ^= d&7
  __shared__ __align__(16) f16 Pl[4][16 * 64]; // per wave [qr][kv], slot ^= qr&7
  const int tid = threadIdx.x, lane = tid & 63, wv = tid >> 6;
  const int bh = blockIdx.y;
  const int b = bh >> 4, h = bh & 15;
  const size_t plane = (size_t)bh * (S_CTX * DH);
  const f16* Qp = q + plane;
  const f16* Kp = kk + plane;
  const f16* Vp = vt + plane;
  const float LOG2E = 1.4426950408889634f;

  for (int half = 0; half < 2; half++) {
    const int qt = half ? (31 - (int)blockIdx.x) : (int)blockIdx.x;
    const int q0 = qt * 64;

    // Q fragments, pre-scaled by log2(e) so softmax runs in exp2 domain
    f16x8 qf[4];
    {
      const f16* qq = Qp + (size_t)(q0 + wv * 16 + (lane & 15)) * DH + ((lane >> 4) * 8);
#pragma unroll
      for (int ks = 0; ks < 4; ks++) {
        qf[ks] = *(const f16x8*)(qq + ks * 32);
#pragma unroll
        for (int e = 0; e < 8; e++) qf[ks][e] = (f16)((float)qf[ks][e] * LOG2E);
      }
    }
    float m_[4], l_[4];
    f32x4 o[8] = {};
#pragma unroll
    for (int r = 0; r < 4; r++) { m_[r] = -3e38f; l_[r] = 0.f; }

    for (int t = 0; t <= qt; t++) {
      __syncthreads();
#pragma unroll
      for (int j = 0; j < 4; j++) {
        int c = tid + j * 256;
        int row = c >> 4, sl = (c & 15) ^ (row & 7);
        gload16(Kp + (size_t)(t * 64 + row) * DH + sl * 8, Ks + c * 8);
      }
#pragma unroll
      for (int j = 0; j < 4; j++) {
        int c = tid + j * 256;
        int row = c >> 3, sl = (c & 7) ^ (row & 7);
        gload16(Vp + (size_t)row * S_CTX + t * 64 + sl * 8, Vs + c * 8);
      }
      __syncthreads();

      // S = Q K^T  (in log2-units: Q pre-scaled)
      f32x4 st[4] = {};
#pragma unroll
      for (int n = 0; n < 4; n++) {
        int rK = n * 16 + (lane & 15);
#pragma unroll
        for (int ks = 0; ks < 4; ks++) {
          int slot = ks * 4 + (lane >> 4);
          f16x8 kf = *(const f16x8*)&Ks[rK * 128 + ((slot ^ (rK & 7)) << 3)];
          st[n] = __builtin_amdgcn_mfma_f32_16x16x32_f16(qf[ks], kf, st[n], 0, 0, 0);
        }
      }
      if (t == qt) {
#pragma unroll
        for (int n = 0; n < 4; n++)
#pragma unroll
          for (int r = 0; r < 4; r++) {
            int kvc = n * 16 + (lane & 15);
            int qr = wv * 16 + (lane >> 4) * 4 + r;
            if (kvc > qr) st[n][r] = -3e38f;
          }
      }
      // online softmax; rows live in 16-lane groups, 4 regs each
      float mx[4];
#pragma unroll
      for (int r = 0; r < 4; r++)
        mx[r] = fmaxf(fmaxf(st[0][r], st[1][r]), fmaxf(st[2][r], st[3][r]));
#pragma unroll
      for (int msk = 1; msk < 16; msk <<= 1)
#pragma unroll
        for (int r = 0; r < 4; r++) mx[r] = fmaxf(mx[r], __shfl_xor(mx[r], msk));
      // defer-max (T13): only rescale when max grew by > 8 (log2 units); P <= 2^8
      bool need = false;
#pragma unroll
      for (int r = 0; r < 4; r++) need = need || (mx[r] > m_[r] + 8.0f);
      if (__any(need)) {
#pragma unroll
        for (int r = 0; r < 4; r++) {
          float nm = fmaxf(m_[r], mx[r]);
          float al = __builtin_amdgcn_exp2f(m_[r] - nm);
          m_[r] = nm;
          l_[r] *= al;
#pragma unroll
          for (int j = 0; j < 8; j++) o[j][r] *= al;
        }
      }
      float ps[4] = {0.f, 0.f, 0.f, 0.f};
      float pvv[4][4];
#pragma unroll
      for (int n = 0; n < 4; n++)
#pragma unroll
        for (int r = 0; r < 4; r++) {
          float p = __builtin_amdgcn_exp2f(st[n][r] - m_[r]);
          pvv[n][r] = p; ps[r] += p;
        }
#pragma unroll
      for (int msk = 1; msk < 16; msk <<= 1)
#pragma unroll
        for (int r = 0; r < 4; r++) ps[r] += __shfl_xor(ps[r], msk);
#pragma unroll
      for (int r = 0; r < 4; r++) l_[r] += ps[r];

      // P -> LDS (C-layout -> A-frag layout)
      f16* Pw = Pl[wv];
#pragma unroll
      for (int n = 0; n < 4; n++)
#pragma unroll
        for (int r = 0; r < 4; r++) {
          int rowp = (lane >> 4) * 4 + r;
          int colp = n * 16 + (lane & 15);
          Pw[rowp * 64 + (((colp >> 3) ^ (rowp & 7)) << 3) + (colp & 7)] = (f16)pvv[n][r];
        }
      // O += P V
#pragma unroll
      for (int ks = 0; ks < 2; ks++) {
        int rowp = lane & 15;
        int slotp = ks * 4 + (lane >> 4);
        f16x8 pa = *(const f16x8*)&Pw[rowp * 64 + ((slotp ^ (rowp & 7)) << 3)];
#pragma unroll
        for (int j = 0; j < 8; j++) {
          int rv = j * 16 + (lane & 15);
          int slotv = ks * 4 + (lane >> 4);
          f16x8 vf = *(const f16x8*)&Vs[rv * 64 + ((slotv ^ (rv & 7)) << 3)];
          o[j] = __builtin_amdgcn_mfma_f32_16x16x32_f16(pa, vf, o[j], 0, 0, 0);
        }
      }
    }

#pragma unroll
    for (int j = 0; j < 8; j++)
#pragma unroll
      for (int r = 0; r < 4; r++) {
        int qr = q0 + wv * 16 + (lane >> 4) * 4 + r;
        int dd = h * 128 + j * 16 + (lane & 15);
        ctx[((size_t)(b * S_CTX + qr) * 2048) + dd] = (f16)(o[j][r] / l_[r]);
      }
  }
}

extern "C" void kernel_launch(void* const* d_in, const int* in_sizes, int n_in,
                              void* d_out, int out_size, void* d_ws, size_t ws_size,
                              hipStream_t stream) {
  (void)in_sizes; (void)n_in; (void)out_size; (void)ws_size;
  const float* x  = (const float*)d_in[0];
  const float* Wq = (const float*)d_in[1];
  const float* Wk = (const float*)d_in[2];
  const float* Wv = (const float*)d_in[3];
  const float* Wo = (const float*)d_in[4];
  float* out = (float*)d_out;
  char* ws = (char*)d_ws;

  // layout (bytes); ctx aliases xb (xb dead after V-projection)
  f16*   xb   = (f16*)(ws);                    // 16,777,216   x fp16 [4096][2048]
  f16*   ctxb = (f16*)(ws);                    // reuse
  f16*   wqT  = (f16*)(ws + 16777216);         // 8,388,608 each, [n][k] fp16
  f16*   wkT  = (f16*)(ws + 25165824);
  f16*   wvT  = (f16*)(ws + 33554432);
  f16*   woT  = (f16*)(ws + 41943040);
  f16*   qb   = (f16*)(ws + 50331648);         // [b,h,s,d] fp16
  f16*   kb   = (f16*)(ws + 67108864);
  f16*   vtb  = (f16*)(ws + 83886080);         // [b,h,d,s] fp16
  float* sint = (float*)(ws + 100663296);      // [2048][64]
  float* cost = (float*)(ws + 101187584);

  rope_tab<<<dim3(512), dim3(256), 0, stream>>>(sint, cost);
  cvt_f32_f16<<<dim3(8192), dim3(256), 0, stream>>>(x, xb);
  wtrans<<<dim3(64, 64, 4), dim3(32, 8), 0, stream>>>(Wq, Wk, Wv, Wo, wqT, wkT, wvT, woT);
  gemm_k<0><<<dim3(16, 32), dim3(256), 0, stream>>>(xb, wqT, qb, nullptr);
  gemm_k<0><<<dim3(16, 32), dim3(256), 0, stream>>>(xb, wkT, kb, nullptr);
  gemm_k<1><<<dim3(16, 32), dim3(256), 0, stream>>>(xb, wvT, vtb, nullptr);
  rope_apply<<<dim3(16384), dim3(256), 0, stream>>>(qb, sint, cost);
  rope_apply<<<dim3(16384), dim3(256), 0, stream>>>(kb, sint, cost);
  attn_k<<<dim3(16, 32), dim3(256), 0, stream>>>(qb, kb, vtb, ctxb);
  gemm_k<2><<<dim3(16, 32), dim3(256), 0, stream>>>(ctxb, woT, nullptr, out);
}